// Round 1
// baseline (10421.524 us; speedup 1.0000x reference)
//
#include <hip/hip_runtime.h>
#include <math.h>

#define T_TOK 2048
#define H_DIM 2048
#define E_NUM 64
#define I_DIM 512
#define TOPK  6
#define TS    32      // tokens per expert tile
#define HC    64      // h-chunk staged in LDS

// ---------------- Router: logits, softmax, top-6, build per-expert lists ----------------
__global__ __launch_bounds__(256) void router_kernel(
    const float* __restrict__ x, const float* __restrict__ gw,
    const float* __restrict__ ebias, float* __restrict__ logits_out,
    int* __restrict__ cnt, int* __restrict__ toklist, float* __restrict__ wtlist)
{
  __shared__ float xs[H_DIM];
  __shared__ float lg[E_NUM];
  int t = blockIdx.x;
  const float4* xp4 = (const float4*)(x + t * H_DIM);
  float4* xs4 = (float4*)xs;
  for (int i = threadIdx.x; i < H_DIM / 4; i += 256) xs4[i] = xp4[i];
  __syncthreads();

  int wave = threadIdx.x >> 6, lane = threadIdx.x & 63;
  for (int ei = 0; ei < 16; ++ei) {
    int e = wave * 16 + ei;
    const float* gwe = gw + e * H_DIM;
    float s = 0.f;
    for (int h = lane; h < H_DIM; h += 64) s = fmaf(xs[h], gwe[h], s);
    for (int off = 32; off; off >>= 1) s += __shfl_down(s, off);
    if (lane == 0) lg[e] = s;
  }
  __syncthreads();

  if (threadIdx.x < E_NUM) logits_out[t * E_NUM + threadIdx.x] = lg[threadIdx.x];

  if (wave == 0) {
    // softmax over 64 experts, one lane per expert
    float v = lg[lane];
    float m = v;
    for (int off = 32; off; off >>= 1) m = fmaxf(m, __shfl_xor(m, off));
    float ex = expf(v - m);
    float sum = ex;
    for (int off = 32; off; off >>= 1) sum += __shfl_xor(sum, off);
    float prob = ex / sum;
    float sc = prob + ebias[lane];   // top-k over bias-corrected score

    int selidx[TOPK]; float selw[TOPK];
    float wsum = 0.f;
    #pragma unroll
    for (int k = 0; k < TOPK; ++k) {
      float mm = sc;
      for (int off = 32; off; off >>= 1) mm = fmaxf(mm, __shfl_xor(mm, off));
      unsigned long long ball = __ballot(sc == mm);
      int sel = __ffsll(ball) - 1;     // lowest-index tie-break (matches lax.top_k)
      float p = __shfl(prob, sel);     // weight from RAW prob
      selidx[k] = sel; selw[k] = p; wsum += p;
      if (lane == sel) sc = -INFINITY;
    }
    if (lane == 0) {
      float inv = 1.f / fmaxf(wsum, 1e-12f);
      #pragma unroll
      for (int k = 0; k < TOPK; ++k) {
        int e = selidx[k];
        int pos = atomicAdd(&cnt[e], 1);
        toklist[e * T_TOK + pos] = t;
        wtlist[e * T_TOK + pos] = selw[k] * inv;
      }
    }
  }
}

// ---------------- Expert FFN: gate/up (SwiGLU) then down, weighted atomic scatter ----------------
__global__ __launch_bounds__(256) void expert_kernel(
    const float* __restrict__ x, const float* __restrict__ gp,
    const float* __restrict__ up, const float* __restrict__ dp,
    const int* __restrict__ cnt, const int* __restrict__ toklist,
    const float* __restrict__ wtlist, float* __restrict__ out)
{
  int e = blockIdx.y;
  int n = cnt[e];
  int base = blockIdx.x * TS;
  if (base >= n) return;
  int nt = min(TS, n - base);

  __shared__ float xs[TS][HC];      // 8 KB
  __shared__ float gs[TS][I_DIM];   // 64 KB
  __shared__ int   stok[TS];
  __shared__ float swt[TS];

  int tid = threadIdx.x;
  if (tid < TS) {
    int src = e * T_TOK + base + ((tid < nt) ? tid : 0);  // clamp OOB rows to row 0
    stok[tid] = toklist[src];
    swt[tid]  = (tid < nt) ? wtlist[e * T_TOK + base + tid] : 0.f;
  }
  __syncthreads();

  const float* wg = gp + e * (H_DIM * I_DIM);
  const float* wu = up + e * (H_DIM * I_DIM);
  const float* wd = dp + e * (I_DIM * H_DIM);
  int c0 = tid, c1 = tid + 256;

  float accA[TS], accB[TS];

  // one H-reduction pass: acc[t][{c0,c1}] += x[t][h] * W[h][c]
  auto pass = [&](const float* __restrict__ W) {
    #pragma unroll
    for (int t = 0; t < TS; ++t) { accA[t] = 0.f; accB[t] = 0.f; }
    for (int hc = 0; hc < H_DIM; hc += HC) {
      __syncthreads();
      {
        int r = tid >> 4, cq = tid & 15;   // 16 float4 per 64-float row
        #pragma unroll
        for (int rr = 0; rr < TS; rr += 16) {
          int row = rr + r;
          ((float4*)xs[row])[cq] = ((const float4*)(x + stok[row] * H_DIM + hc))[cq];
        }
      }
      __syncthreads();
      for (int hh = 0; hh < HC; hh += 4) {
        int h = hc + hh;
        float w00 = W[(h + 0) * I_DIM + c0];
        float w01 = W[(h + 1) * I_DIM + c0];
        float w02 = W[(h + 2) * I_DIM + c0];
        float w03 = W[(h + 3) * I_DIM + c0];
        float w10 = W[(h + 0) * I_DIM + c1];
        float w11 = W[(h + 1) * I_DIM + c1];
        float w12 = W[(h + 2) * I_DIM + c1];
        float w13 = W[(h + 3) * I_DIM + c1];
        #pragma unroll
        for (int t = 0; t < TS; ++t) {
          float4 xv = ((const float4*)xs[t])[hh >> 2];  // LDS broadcast b128
          accA[t] = fmaf(xv.x, w00, accA[t]);
          accA[t] = fmaf(xv.y, w01, accA[t]);
          accA[t] = fmaf(xv.z, w02, accA[t]);
          accA[t] = fmaf(xv.w, w03, accA[t]);
          accB[t] = fmaf(xv.x, w10, accB[t]);
          accB[t] = fmaf(xv.y, w11, accB[t]);
          accB[t] = fmaf(xv.z, w12, accB[t]);
          accB[t] = fmaf(xv.w, w13, accB[t]);
        }
      }
    }
  };

  // ---- gate ----
  pass(wg);
  #pragma unroll
  for (int t = 0; t < TS; ++t) { gs[t][c0] = accA[t]; gs[t][c1] = accB[t]; }
  // ---- up, then SwiGLU combine (own cells only -> no barrier needed) ----
  pass(wu);
  #pragma unroll
  for (int t = 0; t < TS; ++t) {
    float g0 = gs[t][c0], g1 = gs[t][c1];
    gs[t][c0] = g0 / (1.f + expf(-g0)) * accA[t];
    gs[t][c1] = g1 / (1.f + expf(-g1)) * accB[t];
  }
  __syncthreads();

  // ---- down: out[t][j] += (sum_i gs[t][i] * wd[i][j]) * w_t ----
  for (int jg = 0; jg < H_DIM / 256; ++jg) {
    int j = jg * 256 + tid;
    float acc[TS];
    #pragma unroll
    for (int t = 0; t < TS; ++t) acc[t] = 0.f;
    for (int i = 0; i < I_DIM; i += 4) {
      float wd0 = wd[(i + 0) * H_DIM + j];
      float wd1 = wd[(i + 1) * H_DIM + j];
      float wd2 = wd[(i + 2) * H_DIM + j];
      float wd3 = wd[(i + 3) * H_DIM + j];
      #pragma unroll
      for (int t = 0; t < TS; ++t) {
        float4 gv = ((const float4*)gs[t])[i >> 2];   // LDS broadcast b128
        acc[t] = fmaf(gv.x, wd0, acc[t]);
        acc[t] = fmaf(gv.y, wd1, acc[t]);
        acc[t] = fmaf(gv.z, wd2, acc[t]);
        acc[t] = fmaf(gv.w, wd3, acc[t]);
      }
    }
    #pragma unroll
    for (int t = 0; t < TS; ++t) {
      if (t < nt) atomicAdd(&out[stok[t] * H_DIM + j], acc[t] * swt[t]);
    }
  }
}

extern "C" void kernel_launch(void* const* d_in, const int* in_sizes, int n_in,
                              void* d_out, int out_size, void* d_ws, size_t ws_size,
                              hipStream_t stream) {
  const float* hidden = (const float*)d_in[0];
  const float* gate_w = (const float*)d_in[1];
  const float* e_bias = (const float*)d_in[2];
  const float* gate_p = (const float*)d_in[3];
  const float* up_p   = (const float*)d_in[4];
  const float* down_p = (const float*)d_in[5];

  float* out_final  = (float*)d_out;                       // [T, H]
  float* out_logits = out_final + (size_t)T_TOK * H_DIM;   // [T, E]

  // ws layout: [0,256): counts; then token lists (E*T ints); then weight lists (E*T floats)
  int*   cnt     = (int*)d_ws;
  int*   toklist = (int*)((char*)d_ws + 256);
  float* wtlist  = (float*)((char*)d_ws + 256 + (size_t)E_NUM * T_TOK * sizeof(int));

  hipMemsetAsync(d_out, 0, (size_t)T_TOK * H_DIM * sizeof(float), stream);
  hipMemsetAsync(d_ws, 0, 256, stream);

  router_kernel<<<T_TOK, 256, 0, stream>>>(hidden, gate_w, e_bias, out_logits,
                                           cnt, toklist, wtlist);
  expert_kernel<<<dim3(T_TOK / TS, E_NUM), 256, 0, stream>>>(
      hidden, gate_p, up_p, down_p, cnt, toklist, wtlist, out_final);
}

// Round 2
// 879.338 us; speedup vs baseline: 11.8516x; 11.8516x over previous
//
#include <hip/hip_runtime.h>
#include <math.h>

#define T_TOK 2048
#define H_DIM 2048
#define E_NUM 64
#define I_DIM 512
#define TOPK  6

typedef __attribute__((ext_vector_type(8))) short s8;
typedef __attribute__((ext_vector_type(4))) float f4;
typedef __attribute__((ext_vector_type(8))) unsigned short u16x8;

static __device__ __forceinline__ unsigned short f2bf(float f) {
  unsigned int u = __float_as_uint(f);
  u += 0x7fff + ((u >> 16) & 1);          // RNE
  return (unsigned short)(u >> 16);
}
static __device__ __forceinline__ unsigned int pack2(float lo, float hi) {
  return (unsigned int)f2bf(lo) | ((unsigned int)f2bf(hi) << 16);
}

// ---------------- Router: fp32 logits (4 tokens/block), softmax, top-6 selection ----------------
__global__ __launch_bounds__(256) void router_kernel(
    const float* __restrict__ x, const float* __restrict__ gw,
    const float* __restrict__ ebias, float* __restrict__ logits_out,
    int* __restrict__ sel, float* __restrict__ wsel)
{
  __shared__ float xs[4][H_DIM];   // 32 KB
  __shared__ float lg[4][E_NUM];
  int t0 = blockIdx.x * 4;
  int tid = threadIdx.x;
  for (int i = tid; i < 4 * (H_DIM / 4); i += 256) {
    int tt = i >> 9, q = i & 511;   // H_DIM/4 = 512
    ((float4*)xs[tt])[q] = ((const float4*)(x + (size_t)(t0 + tt) * H_DIM))[q];
  }
  __syncthreads();

  int wave = tid >> 6, lane = tid & 63;
  for (int ei = 0; ei < 16; ++ei) {
    int e = wave * 16 + ei;
    const float4* gwe = (const float4*)(gw + (size_t)e * H_DIM);
    float s0 = 0.f, s1 = 0.f, s2 = 0.f, s3 = 0.f;
    for (int h4 = lane; h4 < H_DIM / 4; h4 += 64) {
      float4 w4 = gwe[h4];
      float4 a0 = ((const float4*)xs[0])[h4];
      float4 a1 = ((const float4*)xs[1])[h4];
      float4 a2 = ((const float4*)xs[2])[h4];
      float4 a3 = ((const float4*)xs[3])[h4];
      s0 += w4.x*a0.x + w4.y*a0.y + w4.z*a0.z + w4.w*a0.w;
      s1 += w4.x*a1.x + w4.y*a1.y + w4.z*a1.z + w4.w*a1.w;
      s2 += w4.x*a2.x + w4.y*a2.y + w4.z*a2.z + w4.w*a2.w;
      s3 += w4.x*a3.x + w4.y*a3.y + w4.z*a3.z + w4.w*a3.w;
    }
    for (int off = 32; off; off >>= 1) {
      s0 += __shfl_down(s0, off); s1 += __shfl_down(s1, off);
      s2 += __shfl_down(s2, off); s3 += __shfl_down(s3, off);
    }
    if (lane == 0) { lg[0][e] = s0; lg[1][e] = s1; lg[2][e] = s2; lg[3][e] = s3; }
  }
  __syncthreads();

  { int tt = tid >> 6, e = tid & 63;
    logits_out[(size_t)(t0 + tt) * E_NUM + e] = lg[tt][e]; }

  if (wave == 0) {
    for (int tt = 0; tt < 4; ++tt) {
      int t = t0 + tt;
      float v = lg[tt][lane];
      float m = v;
      for (int off = 32; off; off >>= 1) m = fmaxf(m, __shfl_xor(m, off));
      float ex = __expf(v - m);
      float sum = ex;
      for (int off = 32; off; off >>= 1) sum += __shfl_xor(sum, off);
      float prob = ex / sum;
      float sc = prob + ebias[lane];

      int selidx[TOPK]; float selw[TOPK]; float wsum = 0.f;
      #pragma unroll
      for (int k = 0; k < TOPK; ++k) {
        float mm = sc;
        for (int off = 32; off; off >>= 1) mm = fmaxf(mm, __shfl_xor(mm, off));
        unsigned long long ball = __ballot(sc == mm);
        int s = __ffsll(ball) - 1;          // lowest-index tie-break
        float p = __shfl(prob, s);          // weight from RAW prob
        selidx[k] = s; selw[k] = p; wsum += p;
        if (lane == s) sc = -INFINITY;
      }
      if (lane == 0) {
        float inv = 1.f / fmaxf(wsum, 1e-12f);
        #pragma unroll
        for (int k = 0; k < TOPK; ++k) {
          sel[t * TOPK + k] = selidx[k];
          wsel[t * TOPK + k] = selw[k] * inv;
        }
      }
    }
  }
}

// ---------------- Deterministic ordered per-expert lists ----------------
__global__ __launch_bounds__(64) void build_lists(
    const int* __restrict__ sel, const float* __restrict__ wsel,
    int* __restrict__ cnt, int* __restrict__ toklist, float* __restrict__ wtlist)
{
  int e = blockIdx.x, lane = threadIdx.x;
  int base = 0;
  for (int t0 = 0; t0 < T_TOK; t0 += 64) {
    int t = t0 + lane;
    int flag = 0; float w = 0.f;
    #pragma unroll
    for (int k = 0; k < TOPK; ++k)
      if (sel[t * TOPK + k] == e) { flag = 1; w = wsel[t * TOPK + k]; }
    unsigned long long b = __ballot(flag);
    int pos = base + __popcll(b & ((1ull << lane) - 1ull));
    if (flag) { toklist[e * T_TOK + pos] = t; wtlist[e * T_TOK + pos] = w; }
    base += __popcll(b);
  }
  if (lane == 0) cnt[e] = base;
}

__global__ void scan_kernel(const int* __restrict__ cnt, int* __restrict__ off) {
  if (threadIdx.x == 0) {
    int s = 0;
    for (int e = 0; e < E_NUM; ++e) { off[e] = s; s += cnt[e]; }
  }
}

// ---------------- gate/up GEMM + SwiGLU -> ha (bf16) ----------------
__global__ __launch_bounds__(256) void gateup_kernel(
    const float* __restrict__ x, const float* __restrict__ gp, const float* __restrict__ up,
    const int* __restrict__ cnt, const int* __restrict__ off,
    const int* __restrict__ toklist, unsigned short* __restrict__ ha)
{
  __shared__ unsigned short A_lds[4 * 256 * 8];   // 16 KB  [kg][row][8]
  __shared__ unsigned int   Bt[2][64 * 20];       // 10 KB  [mat][col*20 + hp], stride 80 B
  int e = blockIdx.y, ic = blockIdx.x;
  int n = cnt[e];
  if (n == 0) return;
  int colbase = ic * 64;
  int tid = threadIdx.x, lane = tid & 63, wave = tid >> 6, wbase = wave * 64;
  const float* wg = gp + (size_t)e * (H_DIM * I_DIM) + colbase;
  const float* wu = up + (size_t)e * (H_DIM * I_DIM) + colbase;
  int off_e = off[e];
  int hp = tid & 15, cb = tid >> 4;               // B staging: hpair, col-quad
  int lrow = (lane >> 4) * 4, lcol = lane & 15, kg = lane >> 4;

  for (int tb = 0; tb < n; tb += 256) {
    const float* xrow = x + (size_t)toklist[e * T_TOK + min(tb + tid, n - 1)] * H_DIM;
    f4 accG[4][4], accU[4][4];
    #pragma unroll
    for (int a = 0; a < 4; ++a)
      #pragma unroll
      for (int b = 0; b < 4; ++b) { accG[a][b] = (f4)0.f; accU[a][b] = (f4)0.f; }

    for (int ks = 0; ks < H_DIM / 32; ++ks) {
      int kk = ks * 32;
      __syncthreads();
      { // stage A: one token row per thread, 32 fp32 -> bf16
        const float4* src = (const float4*)(xrow + kk);
        #pragma unroll
        for (int q = 0; q < 4; ++q) {
          float4 a = src[2 * q], b = src[2 * q + 1];
          u16x8 p;
          p[0]=f2bf(a.x); p[1]=f2bf(a.y); p[2]=f2bf(a.z); p[3]=f2bf(a.w);
          p[4]=f2bf(b.x); p[5]=f2bf(b.y); p[6]=f2bf(b.z); p[7]=f2bf(b.w);
          *(u16x8*)&A_lds[(q * 256 + tid) * 8] = p;
        }
      }
      { // stage B (transpose to [col][k] with pad): 2 h-rows x 4 cols per thread, both mats
        size_t roff = (size_t)(kk + 2 * hp) * I_DIM + cb * 4;
        float4 g0 = *(const float4*)(wg + roff);
        float4 g1 = *(const float4*)(wg + roff + I_DIM);
        float4 u0 = *(const float4*)(wu + roff);
        float4 u1 = *(const float4*)(wu + roff + I_DIM);
        unsigned int* dg = &Bt[0][cb * 4 * 20 + hp];
        unsigned int* du = &Bt[1][cb * 4 * 20 + hp];
        dg[0]  = pack2(g0.x, g1.x); dg[20] = pack2(g0.y, g1.y);
        dg[40] = pack2(g0.z, g1.z); dg[60] = pack2(g0.w, g1.w);
        du[0]  = pack2(u0.x, u1.x); du[20] = pack2(u0.y, u1.y);
        du[40] = pack2(u0.z, u1.z); du[60] = pack2(u0.w, u1.w);
      }
      __syncthreads();
      s8 afr[4];
      #pragma unroll
      for (int mf = 0; mf < 4; ++mf)
        afr[mf] = *(s8*)&A_lds[((kg * 256) + wbase + mf * 16 + lcol) * 8];
      #pragma unroll
      for (int nf = 0; nf < 4; ++nf) {
        s8 bg = *(s8*)&Bt[0][(nf * 16 + lcol) * 20 + kg * 4];
        s8 bu = *(s8*)&Bt[1][(nf * 16 + lcol) * 20 + kg * 4];
        #pragma unroll
        for (int mf = 0; mf < 4; ++mf) {
          accG[mf][nf] = __builtin_amdgcn_mfma_f32_16x16x32_bf16(afr[mf], bg, accG[mf][nf], 0, 0, 0);
          accU[mf][nf] = __builtin_amdgcn_mfma_f32_16x16x32_bf16(afr[mf], bu, accU[mf][nf], 0, 0, 0);
        }
      }
    }
    // epilogue: SwiGLU, store bf16 to ha[pair][I]
    #pragma unroll
    for (int mf = 0; mf < 4; ++mf)
      #pragma unroll
      for (int nf = 0; nf < 4; ++nf)
        #pragma unroll
        for (int j = 0; j < 4; ++j) {
          int r = wbase + mf * 16 + lrow + j;
          if (tb + r < n) {
            float g = accG[mf][nf][j], u = accU[mf][nf][j];
            float h = g / (1.f + __expf(-g)) * u;
            ha[(size_t)(off_e + tb + r) * I_DIM + colbase + nf * 16 + lcol] = f2bf(h);
          }
        }
  }
}

// ---------------- down GEMM + weighted atomic scatter ----------------
__global__ __launch_bounds__(256) void down_kernel(
    const unsigned short* __restrict__ ha, const float* __restrict__ dp,
    const int* __restrict__ cnt, const int* __restrict__ off,
    const int* __restrict__ toklist, const float* __restrict__ wtlist,
    float* __restrict__ out)
{
  __shared__ unsigned short A_lds[4 * 256 * 8];   // 16 KB
  __shared__ unsigned int   Bt[64 * 20];          // 5 KB
  __shared__ int   stok[256];
  __shared__ float swt[256];
  int e = blockIdx.y, hc = blockIdx.x;
  int n = cnt[e];
  if (n == 0) return;
  int colbase = hc * 64;
  int tid = threadIdx.x, lane = tid & 63, wave = tid >> 6, wbase = wave * 64;
  const float* wd = dp + (size_t)e * (I_DIM * H_DIM) + colbase;
  int off_e = off[e];
  int hp = tid & 15, cb = tid >> 4;
  int lrow = (lane >> 4) * 4, lcol = lane & 15, kg = lane >> 4;

  for (int tb = 0; tb < n; tb += 256) {
    __syncthreads();     // protect stok/swt rewrite from prior epilogue
    if (tb + tid < n) {
      stok[tid] = toklist[e * T_TOK + tb + tid];
      swt[tid]  = wtlist[e * T_TOK + tb + tid];
    }
    const unsigned short* harow = ha + (size_t)(off_e + min(tb + tid, n - 1)) * I_DIM;
    f4 acc[4][4];
    #pragma unroll
    for (int a = 0; a < 4; ++a)
      #pragma unroll
      for (int b = 0; b < 4; ++b) acc[a][b] = (f4)0.f;

    for (int ks = 0; ks < I_DIM / 32; ++ks) {
      int kk = ks * 32;
      __syncthreads();
      #pragma unroll
      for (int q = 0; q < 4; ++q)    // A: copy 32 bf16 (already bf16)
        *(u16x8*)&A_lds[(q * 256 + tid) * 8] = *(const u16x8*)(harow + kk + q * 8);
      { // B: transpose-stage wd
        size_t roff = (size_t)(kk + 2 * hp) * H_DIM + cb * 4;
        float4 r0 = *(const float4*)(wd + roff);
        float4 r1 = *(const float4*)(wd + roff + H_DIM);
        unsigned int* db = &Bt[cb * 4 * 20 + hp];
        db[0]  = pack2(r0.x, r1.x); db[20] = pack2(r0.y, r1.y);
        db[40] = pack2(r0.z, r1.z); db[60] = pack2(r0.w, r1.w);
      }
      __syncthreads();
      s8 afr[4];
      #pragma unroll
      for (int mf = 0; mf < 4; ++mf)
        afr[mf] = *(s8*)&A_lds[((kg * 256) + wbase + mf * 16 + lcol) * 8];
      #pragma unroll
      for (int nf = 0; nf < 4; ++nf) {
        s8 bb = *(s8*)&Bt[(nf * 16 + lcol) * 20 + kg * 4];
        #pragma unroll
        for (int mf = 0; mf < 4; ++mf)
          acc[mf][nf] = __builtin_amdgcn_mfma_f32_16x16x32_bf16(afr[mf], bb, acc[mf][nf], 0, 0, 0);
      }
    }
    #pragma unroll
    for (int mf = 0; mf < 4; ++mf)
      #pragma unroll
      for (int nf = 0; nf < 4; ++nf)
        #pragma unroll
        for (int j = 0; j < 4; ++j) {
          int r = wbase + mf * 16 + lrow + j;
          if (tb + r < n)
            atomicAdd(&out[(size_t)stok[r] * H_DIM + colbase + nf * 16 + lcol],
                      acc[mf][nf][j] * swt[r]);
        }
  }
}

extern "C" void kernel_launch(void* const* d_in, const int* in_sizes, int n_in,
                              void* d_out, int out_size, void* d_ws, size_t ws_size,
                              hipStream_t stream) {
  const float* hidden = (const float*)d_in[0];
  const float* gate_w = (const float*)d_in[1];
  const float* e_bias = (const float*)d_in[2];
  const float* gate_p = (const float*)d_in[3];
  const float* up_p   = (const float*)d_in[4];
  const float* down_p = (const float*)d_in[5];

  float* out_final  = (float*)d_out;                       // [T, H]
  float* out_logits = out_final + (size_t)T_TOK * H_DIM;   // [T, E]

  int*   cnt     = (int*)d_ws;
  int*   off     = cnt + 64;
  int*   sel     = off + 64;
  float* wsel    = (float*)(sel + T_TOK * TOPK);
  int*   toklist = (int*)(wsel + T_TOK * TOPK);
  float* wtlist  = (float*)(toklist + E_NUM * T_TOK);
  unsigned short* ha = (unsigned short*)(wtlist + E_NUM * T_TOK);  // 12288*512 bf16

  hipMemsetAsync(out_final, 0, (size_t)T_TOK * H_DIM * sizeof(float), stream);

  router_kernel<<<T_TOK / 4, 256, 0, stream>>>(hidden, gate_w, e_bias, out_logits, sel, wsel);
  build_lists<<<E_NUM, 64, 0, stream>>>(sel, wsel, cnt, toklist, wtlist);
  scan_kernel<<<1, 64, 0, stream>>>(cnt, off);
  gateup_kernel<<<dim3(I_DIM / 64, E_NUM), 256, 0, stream>>>(
      hidden, gate_p, up_p, cnt, off, toklist, ha);
  down_kernel<<<dim3(H_DIM / 64, E_NUM), 256, 0, stream>>>(
      ha, down_p, cnt, off, toklist, wtlist, out_final);
}

// Round 3
// 629.356 us; speedup vs baseline: 16.5590x; 1.3972x over previous
//
#include <hip/hip_runtime.h>
#include <math.h>

#define T_TOK 2048
#define H_DIM 2048
#define E_NUM 64
#define I_DIM 512
#define TOPK  6

typedef __attribute__((ext_vector_type(8))) short s8;
typedef __attribute__((ext_vector_type(4))) float f4;
typedef __attribute__((ext_vector_type(8))) unsigned short u16x8;

static __device__ __forceinline__ unsigned short f2bf(float f) {
  unsigned int u = __float_as_uint(f);
  u += 0x7fff + ((u >> 16) & 1);          // RNE
  return (unsigned short)(u >> 16);
}
static __device__ __forceinline__ unsigned int pack2(float lo, float hi) {
  return (unsigned int)f2bf(lo) | ((unsigned int)f2bf(hi) << 16);
}

// ---------------- Router: fp32 logits (4 tokens/block), softmax, top-6 selection ----------------
__global__ __launch_bounds__(256) void router_kernel(
    const float* __restrict__ x, const float* __restrict__ gw,
    const float* __restrict__ ebias, float* __restrict__ logits_out,
    int* __restrict__ sel, float* __restrict__ wsel)
{
  __shared__ float xs[4][H_DIM];   // 32 KB
  __shared__ float lg[4][E_NUM];
  int t0 = blockIdx.x * 4;
  int tid = threadIdx.x;
  for (int i = tid; i < 4 * (H_DIM / 4); i += 256) {
    int tt = i >> 9, q = i & 511;   // H_DIM/4 = 512
    ((float4*)xs[tt])[q] = ((const float4*)(x + (size_t)(t0 + tt) * H_DIM))[q];
  }
  __syncthreads();

  int wave = tid >> 6, lane = tid & 63;
  for (int ei = 0; ei < 16; ++ei) {
    int e = wave * 16 + ei;
    const float4* gwe = (const float4*)(gw + (size_t)e * H_DIM);
    float s0 = 0.f, s1 = 0.f, s2 = 0.f, s3 = 0.f;
    for (int h4 = lane; h4 < H_DIM / 4; h4 += 64) {
      float4 w4 = gwe[h4];
      float4 a0 = ((const float4*)xs[0])[h4];
      float4 a1 = ((const float4*)xs[1])[h4];
      float4 a2 = ((const float4*)xs[2])[h4];
      float4 a3 = ((const float4*)xs[3])[h4];
      s0 += w4.x*a0.x + w4.y*a0.y + w4.z*a0.z + w4.w*a0.w;
      s1 += w4.x*a1.x + w4.y*a1.y + w4.z*a1.z + w4.w*a1.w;
      s2 += w4.x*a2.x + w4.y*a2.y + w4.z*a2.z + w4.w*a2.w;
      s3 += w4.x*a3.x + w4.y*a3.y + w4.z*a3.z + w4.w*a3.w;
    }
    for (int off = 32; off; off >>= 1) {
      s0 += __shfl_down(s0, off); s1 += __shfl_down(s1, off);
      s2 += __shfl_down(s2, off); s3 += __shfl_down(s3, off);
    }
    if (lane == 0) { lg[0][e] = s0; lg[1][e] = s1; lg[2][e] = s2; lg[3][e] = s3; }
  }
  __syncthreads();

  { int tt = tid >> 6, e = tid & 63;
    logits_out[(size_t)(t0 + tt) * E_NUM + e] = lg[tt][e]; }

  if (wave == 0) {
    for (int tt = 0; tt < 4; ++tt) {
      int t = t0 + tt;
      float v = lg[tt][lane];
      float m = v;
      for (int off = 32; off; off >>= 1) m = fmaxf(m, __shfl_xor(m, off));
      float ex = __expf(v - m);
      float sum = ex;
      for (int off = 32; off; off >>= 1) sum += __shfl_xor(sum, off);
      float prob = ex / sum;
      float sc = prob + ebias[lane];

      int selidx[TOPK]; float selw[TOPK]; float wsum = 0.f;
      #pragma unroll
      for (int k = 0; k < TOPK; ++k) {
        float mm = sc;
        for (int off = 32; off; off >>= 1) mm = fmaxf(mm, __shfl_xor(mm, off));
        unsigned long long ball = __ballot(sc == mm);
        int s = __ffsll(ball) - 1;          // lowest-index tie-break
        float p = __shfl(prob, s);          // weight from RAW prob
        selidx[k] = s; selw[k] = p; wsum += p;
        if (lane == s) sc = -INFINITY;
      }
      if (lane == 0) {
        float inv = 1.f / fmaxf(wsum, 1e-12f);
        #pragma unroll
        for (int k = 0; k < TOPK; ++k) {
          sel[t * TOPK + k] = selidx[k];
          wsel[t * TOPK + k] = selw[k] * inv;
        }
      }
    }
  }
}

// ---------------- Deterministic ordered per-expert lists ----------------
__global__ __launch_bounds__(64) void build_lists(
    const int* __restrict__ sel, const float* __restrict__ wsel,
    int* __restrict__ cnt, int* __restrict__ toklist, float* __restrict__ wtlist)
{
  int e = blockIdx.x, lane = threadIdx.x;
  int base = 0;
  for (int t0 = 0; t0 < T_TOK; t0 += 64) {
    int t = t0 + lane;
    int flag = 0; float w = 0.f;
    #pragma unroll
    for (int k = 0; k < TOPK; ++k)
      if (sel[t * TOPK + k] == e) { flag = 1; w = wsel[t * TOPK + k]; }
    unsigned long long b = __ballot(flag);
    int pos = base + __popcll(b & ((1ull << lane) - 1ull));
    if (flag) { toklist[e * T_TOK + pos] = t; wtlist[e * T_TOK + pos] = w; }
    base += __popcll(b);
  }
  if (lane == 0) cnt[e] = base;
}

__global__ void scan_kernel(const int* __restrict__ cnt, int* __restrict__ off) {
  if (threadIdx.x == 0) {
    int s = 0;
    for (int e = 0; e < E_NUM; ++e) { off[e] = s; s += cnt[e]; }
  }
}

// ---------------- gate/up GEMM + SwiGLU -> ha (bf16) ----------------
// 512 threads: waves 0-3 compute GATE, waves 4-7 compute UP (same 256x64 tile).
// Double-buffered LDS, register prefetch of next K-step.
__global__ __launch_bounds__(512, 4) void gateup_kernel(
    const float* __restrict__ x, const float* __restrict__ gp, const float* __restrict__ up,
    const int* __restrict__ cnt, const int* __restrict__ off,
    const int* __restrict__ toklist, unsigned short* __restrict__ ha)
{
  __shared__ __align__(16) unsigned short A_lds[2][4 * 256 * 8];  // 2 x 16 KB [kg][row][8]
  __shared__ __align__(16) unsigned int   Bt[2][2][64 * 20];      // 2 x 10 KB [mat][col*20+hp]
  int e = blockIdx.y, ic = blockIdx.x;
  int n = cnt[e];
  if (n == 0) return;
  int colbase = ic * 64;
  int tid = threadIdx.x, lane = tid & 63, wave = tid >> 6;
  int off_e = off[e];
  int matc = wave >> 2;                 // compute role: 0=gate, 1=up
  int cw = wave & 3;                    // compute row-block within 256
  int lrow = (lane >> 4) * 4, lcol = lane & 15, kg = lane >> 4;

  // staging roles
  int arow_loc = tid >> 1, khalf = tid & 1;                 // A: row, k-half
  int g8 = tid & 255, hp = g8 & 15, cb = g8 >> 4;           // B: h-pair, col-quad
  const float* wmat = ((tid < 256) ? gp : up) + (size_t)e * (H_DIM * I_DIM) + colbase;

  for (int tb = 0; tb < n; tb += 256) {
    const float* xrow = x + (size_t)toklist[e * T_TOK + min(tb + arow_loc, n - 1)] * H_DIM
                        + khalf * 16;
    float4 pa0, pa1, pa2, pa3, pb0, pb1;

    auto issue = [&](int ks) {
      const float4* asrc = (const float4*)(xrow + ks * 32);
      pa0 = asrc[0]; pa1 = asrc[1]; pa2 = asrc[2]; pa3 = asrc[3];
      const float* bsrc = wmat + (size_t)(ks * 32 + 2 * hp) * I_DIM + cb * 4;
      pb0 = *(const float4*)bsrc;
      pb1 = *(const float4*)(bsrc + I_DIM);
    };
    auto commit = [&](int buf) {
      u16x8 q0, q1;
      q0[0]=f2bf(pa0.x); q0[1]=f2bf(pa0.y); q0[2]=f2bf(pa0.z); q0[3]=f2bf(pa0.w);
      q0[4]=f2bf(pa1.x); q0[5]=f2bf(pa1.y); q0[6]=f2bf(pa1.z); q0[7]=f2bf(pa1.w);
      q1[0]=f2bf(pa2.x); q1[1]=f2bf(pa2.y); q1[2]=f2bf(pa2.z); q1[3]=f2bf(pa2.w);
      q1[4]=f2bf(pa3.x); q1[5]=f2bf(pa3.y); q1[6]=f2bf(pa3.z); q1[7]=f2bf(pa3.w);
      *(u16x8*)&A_lds[buf][((khalf * 2 + 0) * 256 + arow_loc) * 8] = q0;
      *(u16x8*)&A_lds[buf][((khalf * 2 + 1) * 256 + arow_loc) * 8] = q1;
      unsigned int* db = &Bt[buf][tid >> 8][cb * 4 * 20 + hp];
      db[0]  = pack2(pb0.x, pb1.x); db[20] = pack2(pb0.y, pb1.y);
      db[40] = pack2(pb0.z, pb1.z); db[60] = pack2(pb0.w, pb1.w);
    };

    f4 acc[4][4];
    #pragma unroll
    for (int a = 0; a < 4; ++a)
      #pragma unroll
      for (int b = 0; b < 4; ++b) acc[a][b] = (f4)0.f;

    issue(0);
    commit(0);
    int cur = 0;
    for (int ks = 0; ks < H_DIM / 32; ++ks) {
      __syncthreads();
      if (ks + 1 < H_DIM / 32) issue(ks + 1);
      s8 afr[4];
      #pragma unroll
      for (int mf = 0; mf < 4; ++mf)
        afr[mf] = *(s8*)&A_lds[cur][((kg * 256) + cw * 64 + mf * 16 + lcol) * 8];
      #pragma unroll
      for (int nf = 0; nf < 4; ++nf) {
        s8 bf = *(s8*)&Bt[cur][matc][(nf * 16 + lcol) * 20 + kg * 4];
        #pragma unroll
        for (int mf = 0; mf < 4; ++mf)
          acc[mf][nf] = __builtin_amdgcn_mfma_f32_16x16x32_bf16(afr[mf], bf, acc[mf][nf], 0, 0, 0);
      }
      if (ks + 1 < H_DIM / 32) commit(cur ^ 1);
      cur ^= 1;
    }

    // ---- SwiGLU epilogue: up waves ship U to gate waves via LDS (reuse A buffer) ----
    f4* exch = (f4*)&A_lds[0][0];   // 1024 f4 = 16 KB per chunk
    #pragma unroll
    for (int nf = 0; nf < 4; ++nf) {
      __syncthreads();
      if (wave >= 4) {
        #pragma unroll
        for (int mf = 0; mf < 4; ++mf)
          exch[((wave - 4) * 4 + mf) * 64 + lane] = acc[mf][nf];
      }
      __syncthreads();
      if (wave < 4) {
        #pragma unroll
        for (int mf = 0; mf < 4; ++mf) {
          f4 u = exch[(wave * 4 + mf) * 64 + lane];
          #pragma unroll
          for (int j = 0; j < 4; ++j) {
            int r = wave * 64 + mf * 16 + lrow + j;
            if (tb + r < n) {
              float g = acc[mf][nf][j];
              float h = g / (1.f + __expf(-g)) * u[j];
              ha[(size_t)(off_e + tb + r) * I_DIM + colbase + nf * 16 + lcol] = f2bf(h);
            }
          }
        }
      }
    }
    __syncthreads();   // exch (A_lds[0]) dead before next tile's commit(0)
  }
}

// ---------------- down GEMM + weighted atomic scatter (dbuf + prefetch) ----------------
__global__ __launch_bounds__(256, 4) void down_kernel(
    const unsigned short* __restrict__ ha, const float* __restrict__ dp,
    const int* __restrict__ cnt, const int* __restrict__ off,
    const int* __restrict__ toklist, const float* __restrict__ wtlist,
    float* __restrict__ out)
{
  __shared__ __align__(16) unsigned short A_lds[2][4 * 256 * 8];  // 2 x 16 KB
  __shared__ __align__(16) unsigned int   Bt[2][64 * 20];         // 2 x 5 KB
  __shared__ int   stok[256];
  __shared__ float swt[256];
  int e = blockIdx.y, hc = blockIdx.x;
  int n = cnt[e];
  if (n == 0) return;
  int colbase = hc * 64;
  int tid = threadIdx.x, lane = tid & 63, wave = tid >> 6, wbase = wave * 64;
  const float* wd = dp + (size_t)e * (I_DIM * H_DIM) + colbase;
  int off_e = off[e];
  int hp = tid & 15, cb = tid >> 4;
  int lrow = (lane >> 4) * 4, lcol = lane & 15, kg = lane >> 4;

  for (int tb = 0; tb < n; tb += 256) {
    __syncthreads();     // protect stok/swt + LDS bufs from prior tile
    if (tb + tid < n) {
      stok[tid] = toklist[e * T_TOK + tb + tid];
      swt[tid]  = wtlist[e * T_TOK + tb + tid];
    }
    const unsigned short* harow = ha + (size_t)(off_e + min(tb + tid, n - 1)) * I_DIM;

    u16x8 qa0, qa1, qa2, qa3; float4 qb0, qb1;
    auto issue = [&](int ks) {
      const u16x8* asrc = (const u16x8*)(harow + ks * 32);
      qa0 = asrc[0]; qa1 = asrc[1]; qa2 = asrc[2]; qa3 = asrc[3];
      const float* bsrc = wd + (size_t)(ks * 32 + 2 * hp) * H_DIM + cb * 4;
      qb0 = *(const float4*)bsrc;
      qb1 = *(const float4*)(bsrc + H_DIM);
    };
    auto commit = [&](int buf) {
      *(u16x8*)&A_lds[buf][(0 * 256 + tid) * 8] = qa0;
      *(u16x8*)&A_lds[buf][(1 * 256 + tid) * 8] = qa1;
      *(u16x8*)&A_lds[buf][(2 * 256 + tid) * 8] = qa2;
      *(u16x8*)&A_lds[buf][(3 * 256 + tid) * 8] = qa3;
      unsigned int* db = &Bt[buf][cb * 4 * 20 + hp];
      db[0]  = pack2(qb0.x, qb1.x); db[20] = pack2(qb0.y, qb1.y);
      db[40] = pack2(qb0.z, qb1.z); db[60] = pack2(qb0.w, qb1.w);
    };

    f4 acc[4][4];
    #pragma unroll
    for (int a = 0; a < 4; ++a)
      #pragma unroll
      for (int b = 0; b < 4; ++b) acc[a][b] = (f4)0.f;

    issue(0);
    commit(0);
    int cur = 0;
    for (int ks = 0; ks < I_DIM / 32; ++ks) {
      __syncthreads();
      if (ks + 1 < I_DIM / 32) issue(ks + 1);
      s8 afr[4];
      #pragma unroll
      for (int mf = 0; mf < 4; ++mf)
        afr[mf] = *(s8*)&A_lds[cur][((kg * 256) + wbase + mf * 16 + lcol) * 8];
      #pragma unroll
      for (int nf = 0; nf < 4; ++nf) {
        s8 bb = *(s8*)&Bt[cur][(nf * 16 + lcol) * 20 + kg * 4];
        #pragma unroll
        for (int mf = 0; mf < 4; ++mf)
          acc[mf][nf] = __builtin_amdgcn_mfma_f32_16x16x32_bf16(afr[mf], bb, acc[mf][nf], 0, 0, 0);
      }
      if (ks + 1 < I_DIM / 32) commit(cur ^ 1);
      cur ^= 1;
    }

    #pragma unroll
    for (int mf = 0; mf < 4; ++mf)
      #pragma unroll
      for (int nf = 0; nf < 4; ++nf)
        #pragma unroll
        for (int j = 0; j < 4; ++j) {
          int r = wbase + mf * 16 + lrow + j;
          if (tb + r < n)
            atomicAdd(&out[(size_t)stok[r] * H_DIM + colbase + nf * 16 + lcol],
                      acc[mf][nf][j] * swt[r]);
        }
  }
}

extern "C" void kernel_launch(void* const* d_in, const int* in_sizes, int n_in,
                              void* d_out, int out_size, void* d_ws, size_t ws_size,
                              hipStream_t stream) {
  const float* hidden = (const float*)d_in[0];
  const float* gate_w = (const float*)d_in[1];
  const float* e_bias = (const float*)d_in[2];
  const float* gate_p = (const float*)d_in[3];
  const float* up_p   = (const float*)d_in[4];
  const float* down_p = (const float*)d_in[5];

  float* out_final  = (float*)d_out;                       // [T, H]
  float* out_logits = out_final + (size_t)T_TOK * H_DIM;   // [T, E]

  int*   cnt     = (int*)d_ws;
  int*   off     = cnt + 64;
  int*   sel     = off + 64;
  float* wsel    = (float*)(sel + T_TOK * TOPK);
  int*   toklist = (int*)(wsel + T_TOK * TOPK);
  float* wtlist  = (float*)(toklist + E_NUM * T_TOK);
  unsigned short* ha = (unsigned short*)(wtlist + E_NUM * T_TOK);  // 12288*512 bf16

  hipMemsetAsync(out_final, 0, (size_t)T_TOK * H_DIM * sizeof(float), stream);

  router_kernel<<<T_TOK / 4, 256, 0, stream>>>(hidden, gate_w, e_bias, out_logits, sel, wsel);
  build_lists<<<E_NUM, 64, 0, stream>>>(sel, wsel, cnt, toklist, wtlist);
  scan_kernel<<<1, 64, 0, stream>>>(cnt, off);
  gateup_kernel<<<dim3(I_DIM / 64, E_NUM), 512, 0, stream>>>(
      hidden, gate_p, up_p, cnt, off, toklist, ha);
  down_kernel<<<dim3(H_DIM / 64, E_NUM), 256, 0, stream>>>(
      ha, down_p, cnt, off, toklist, wtlist, out_final);
}